// Round 13
// baseline (283.643 us; speedup 1.0000x reference)
//
#include <hip/hip_runtime.h>
#include <math.h>

#define N_NODES   100000
#define N_HALF    50000              // src-half split for L2 residency
#define N_EDGES   3200000
#define D_IN      128
#define H_DIM     32
#define OUT_DIM   16
#define NB        391                // buckets = ceil(N / 256), bucket = dst >> 8
#define B1        512                // blocks in pass 1 / pass 3
#define CHUNK     6272               // edges per block (512*6272 >= 3.2M; 16B-aligned base)
#define NHIST     (NB * B1)          // 200192 histogram entries
#define SUMS_N    (NHIST / 256)      // 782 scan partials
#define SCANB_PER 4                  // 256*4 >= 782

typedef _Float16 half_t;
typedef __attribute__((ext_vector_type(4))) _Float16 half4;   // 8-byte
typedef __attribute__((ext_vector_type(8))) _Float16 half8;   // 16-byte

#define PACK(d, s) ((((unsigned int)(d) & 255u) << 17) | (unsigned int)(s))

// ---------------- pass 1: bucket histogram (LDS atomics, int4 reads, 4-way ILP) ----------------

__global__ __launch_bounds__(256) void k_p1_hist(const int* __restrict__ dst,
                                                 int* __restrict__ hist_g) {
    __shared__ int hist[NB];
    int t = threadIdx.x;
    for (int i = t; i < NB; i += 256) hist[i] = 0;
    __syncthreads();
    int base = blockIdx.x * CHUNK;
    for (int k = t * 4; k < CHUNK; k += 1024) {
        int e = base + k;
        if (k + 4 <= CHUNK && e + 4 <= N_EDGES) {
            int4 d = *(const int4*)(dst + e);
            atomicAdd(&hist[d.x >> 8], 1);
            atomicAdd(&hist[d.y >> 8], 1);
            atomicAdd(&hist[d.z >> 8], 1);
            atomicAdd(&hist[d.w >> 8], 1);
        } else {
            for (int kk = k; kk < CHUNK && base + kk < N_EDGES; ++kk)
                atomicAdd(&hist[dst[base + kk] >> 8], 1);
        }
    }
    __syncthreads();
    for (int i = t; i < NB; i += 256) hist_g[i * B1 + blockIdx.x] = hist[i];
}

// ---------------- pass 2: 3-kernel exclusive scan of hist_g ----------------

__global__ __launch_bounds__(256) void k_scanA(const int* __restrict__ hist_g,
                                               int* __restrict__ sums) {
    __shared__ int s[256];
    int t = threadIdx.x;
    s[t] = hist_g[blockIdx.x * 256 + t];
    __syncthreads();
    for (int off = 128; off > 0; off >>= 1) {
        if (t < off) s[t] += s[t + off];
        __syncthreads();
    }
    if (t == 0) sums[blockIdx.x] = s[0];
}

__global__ __launch_bounds__(256) void k_scanB(int* sums) {
    __shared__ int a[256], b[256];
    int t = threadIdx.x;
    int base = t * SCANB_PER;
    int v[SCANB_PER];
    int tot = 0;
#pragma unroll
    for (int k = 0; k < SCANB_PER; ++k) {
        v[k] = (base + k < SUMS_N) ? sums[base + k] : 0;
        tot += v[k];
    }
    a[t] = tot;
    __syncthreads();
    int* cur = a; int* nxt = b;
    for (int off = 1; off < 256; off <<= 1) {
        nxt[t] = cur[t] + ((t >= off) ? cur[t - off] : 0);
        __syncthreads();
        int* tmp = cur; cur = nxt; nxt = tmp;
    }
    int run = cur[t] - tot;                      // exclusive prefix of this chunk
#pragma unroll
    for (int k = 0; k < SCANB_PER; ++k) {
        if (base + k < SUMS_N) sums[base + k] = run;
        run += v[k];
    }
}

__global__ __launch_bounds__(256) void k_scanC(int* hist_g, const int* __restrict__ sums) {
    __shared__ int a[256], b[256];
    int t = threadIdx.x;
    int v = hist_g[blockIdx.x * 256 + t];
    a[t] = v;
    __syncthreads();
    int* cur = a; int* nxt = b;
    for (int off = 1; off < 256; off <<= 1) {
        nxt[t] = cur[t] + ((t >= off) ? cur[t - off] : 0);
        __syncthreads();
        int* tmp = cur; cur = nxt; nxt = tmp;
    }
    hist_g[blockIdx.x * 256 + t] = sums[blockIdx.x] + cur[t] - v;   // exclusive
}

// ---------------- pass 3: scatter packed pairs (int4 reads, 4 independent chains) ----------------

__global__ __launch_bounds__(256) void k_p3(const int* __restrict__ src,
                                            const int* __restrict__ dst,
                                            const int* __restrict__ hist_g,
                                            unsigned int* __restrict__ pairs) {
    __shared__ int cur[NB];
    int t = threadIdx.x;
    for (int i = t; i < NB; i += 256) cur[i] = hist_g[i * B1 + blockIdx.x];
    __syncthreads();
    int base = blockIdx.x * CHUNK;
    for (int k = t * 4; k < CHUNK; k += 1024) {
        int e = base + k;
        if (k + 4 <= CHUNK && e + 4 <= N_EDGES) {
            int4 d = *(const int4*)(dst + e);
            int4 s = *(const int4*)(src + e);
            int p0 = atomicAdd(&cur[d.x >> 8], 1);
            int p1 = atomicAdd(&cur[d.y >> 8], 1);
            int p2 = atomicAdd(&cur[d.z >> 8], 1);
            int p3 = atomicAdd(&cur[d.w >> 8], 1);
            pairs[p0] = PACK(d.x, s.x);
            pairs[p1] = PACK(d.y, s.y);
            pairs[p2] = PACK(d.z, s.z);
            pairs[p3] = PACK(d.w, s.w);
        } else {
            for (int kk = k; kk < CHUNK && base + kk < N_EDGES; ++kk) {
                int d = dst[base + kk];
                int pos = atomicAdd(&cur[d >> 8], 1);
                pairs[pos] = PACK(d, src[base + kk]);
            }
        }
    }
}

// ---------------- pass 4: per-bucket grouping by (node, src-half), 2-way ILP ----------------

__global__ __launch_bounds__(512) void k_p4(const unsigned int* __restrict__ pairs,
                                            const int* __restrict__ hist_g,
                                            int* __restrict__ csr_src,
                                            int* __restrict__ row_ptr,
                                            int* __restrict__ row_mid,
                                            float* __restrict__ dinv) {
    __shared__ int cnt[512], a[512], b[512], cur[512];
    int t = threadIdx.x;
    int bk = blockIdx.x;
    int lo = hist_g[bk * B1];
    int hi = (bk + 1 < NB) ? hist_g[(bk + 1) * B1] : N_EDGES;

    cnt[t] = 0;
    __syncthreads();
    {
        int j = lo + t;
        for (; j + 512 < hi; j += 1024) {
            unsigned int p = pairs[j], q = pairs[j + 512];
            int sp = (int)(p & 0x1FFFFu), sq = (int)(q & 0x1FFFFu);
            atomicAdd(&cnt[(int)((p >> 17) << 1) | (sp >= N_HALF)], 1);
            atomicAdd(&cnt[(int)((q >> 17) << 1) | (sq >= N_HALF)], 1);
        }
        for (; j < hi; j += 512) {
            unsigned int p = pairs[j];
            int sp = (int)(p & 0x1FFFFu);
            atomicAdd(&cnt[(int)((p >> 17) << 1) | (sp >= N_HALF)], 1);
        }
    }
    __syncthreads();

    a[t] = cnt[t];
    __syncthreads();
    int* c0 = a; int* c1 = b;
    for (int off = 1; off < 512; off <<= 1) {
        c1[t] = c0[t] + ((t >= off) ? c0[t - off] : 0);
        __syncthreads();
        int* tmp = c0; c0 = c1; c1 = tmp;
    }
    int excl = c0[t] - cnt[t];
    cur[t] = lo + excl;

    int node = bk * 256 + (t >> 1);
    if (node < N_NODES) {
        if ((t & 1) == 0) {
            row_ptr[node] = lo + excl;
            dinv[node] = rsqrtf((float)(cnt[t] + cnt[t + 1]) + 1.0f);  // +1 self-loop
        } else {
            row_mid[node] = lo + excl;
        }
    }
    if (bk == NB - 1 && t == 0) row_ptr[N_NODES] = N_EDGES;
    __syncthreads();

    {
        int j = lo + t;
        for (; j + 512 < hi; j += 1024) {
            unsigned int p = pairs[j], q = pairs[j + 512];
            int sp = (int)(p & 0x1FFFFu), sq = (int)(q & 0x1FFFFu);
            int pp = atomicAdd(&cur[(int)((p >> 17) << 1) | (sp >= N_HALF)], 1);
            int pq = atomicAdd(&cur[(int)((q >> 17) << 1) | (sq >= N_HALF)], 1);
            csr_src[pp] = sp;
            csr_src[pq] = sq;
        }
        for (; j < hi; j += 512) {
            unsigned int p = pairs[j];
            int sp = (int)(p & 0x1FFFFu);
            int pp = atomicAdd(&cur[(int)((p >> 17) << 1) | (sp >= N_HALF)], 1);
            csr_src[pp] = sp;
        }
    }
}

// ---------------- layer 1: hs = fp16( dinv[i] * (x @ W1) ) ----------------

__global__ __launch_bounds__(256) void k_gemm1(const float* __restrict__ x,
                                               const float* __restrict__ W1,
                                               const float* __restrict__ dinv,
                                               half_t* __restrict__ hs) {
    int i = blockIdx.x * 256 + threadIdx.x;
    if (i >= N_NODES) return;

    const float* xr = x + (size_t)i * D_IN;
    float acc[H_DIM];
#pragma unroll
    for (int c = 0; c < H_DIM; ++c) acc[c] = 0.f;

    for (int k0 = 0; k0 < D_IN; k0 += 4) {       // 32 iterations
        float4 xv = *(const float4*)(xr + k0);
#pragma unroll
        for (int kk = 0; kk < 4; ++kk) {
            float xk = (kk == 0) ? xv.x : (kk == 1) ? xv.y : (kk == 2) ? xv.z : xv.w;
            const float* wr = W1 + (k0 + kk) * H_DIM;   // uniform address -> s_load
#pragma unroll
            for (int c = 0; c < H_DIM; ++c)
                acc[c] = fmaf(xk, wr[c], acc[c]);
        }
    }

    float di = dinv[i];
    half_t* o = hs + (size_t)i * H_DIM;
#pragma unroll
    for (int c4 = 0; c4 < H_DIM / 4; ++c4) {
        half4 ov;
        ov.x = (half_t)(acc[c4 * 4 + 0] * di);
        ov.y = (half_t)(acc[c4 * 4 + 1] * di);
        ov.z = (half_t)(acc[c4 * 4 + 2] * di);
        ov.w = (half_t)(acc[c4 * 4 + 3] * di);
        *(half4*)(o + c4 * 4) = ov;
    }
}

// ---------------- pipelined gather core (layer 1): cur/nxt index double-buffer ----------------

__device__ __forceinline__ void g1_loop(const half8* __restrict__ hp,
                                        const int* __restrict__ csr,
                                        int start, int end, int c, float acc[8]) {
    int j = start;
    int cur[8], nxt[8];
    if (j + 8 <= end) {
#pragma unroll
        for (int u = 0; u < 8; ++u) cur[u] = csr[j + u];
    }
    for (; j + 16 <= end; j += 8) {
#pragma unroll
        for (int u = 0; u < 8; ++u) nxt[u] = csr[j + 8 + u];   // prefetch next batch
        half8 v[8];
#pragma unroll
        for (int u = 0; u < 8; ++u) v[u] = hp[(size_t)cur[u] * 4 + c];
#pragma unroll
        for (int u = 0; u < 8; ++u)
#pragma unroll
            for (int k = 0; k < 8; ++k) acc[k] += (float)v[u][k];
#pragma unroll
        for (int u = 0; u < 8; ++u) cur[u] = nxt[u];
    }
    if (j + 8 <= end) {
        half8 v[8];
#pragma unroll
        for (int u = 0; u < 8; ++u) v[u] = hp[(size_t)cur[u] * 4 + c];
#pragma unroll
        for (int u = 0; u < 8; ++u)
#pragma unroll
            for (int k = 0; k < 8; ++k) acc[k] += (float)v[u][k];
        j += 8;
    }
    for (; j < end; ++j) {
        half8 v = hp[(size_t)csr[j] * 4 + c];
#pragma unroll
        for (int k = 0; k < 8; ++k) acc[k] += (float)v[k];
    }
}

// ---------------- layer-1 aggregation, pass A: low-half sources only ----------------

__global__ __launch_bounds__(256) void k_gather1A(const int* __restrict__ row_ptr,
                                                  const int* __restrict__ row_mid,
                                                  const int* __restrict__ csr_src,
                                                  const half_t* __restrict__ hs,
                                                  half_t* __restrict__ h_part) {
    int t = blockIdx.x * 256 + threadIdx.x;
    int i = t >> 2, c = t & 3;
    if (i >= N_NODES) return;

    float acc[8];
#pragma unroll
    for (int k = 0; k < 8; ++k) acc[k] = 0.f;
    g1_loop((const half8*)hs, csr_src, row_ptr[i], row_mid[i], c, acc);

    half8 o;
#pragma unroll
    for (int k = 0; k < 8; ++k) o[k] = (half_t)acc[k];
    ((half8*)h_part)[(size_t)i * 4 + c] = o;
}

// ---------------- layer-1 aggregation, pass B: high-half + self + bias + relu ----------------

__global__ __launch_bounds__(256) void k_gather1B(const int* __restrict__ row_ptr,
                                                  const int* __restrict__ row_mid,
                                                  const int* __restrict__ csr_src,
                                                  const float* __restrict__ dinv,
                                                  const half_t* __restrict__ hs,
                                                  const half_t* __restrict__ h_part,
                                                  const float* __restrict__ b1,
                                                  half_t* __restrict__ h) {
    int t = blockIdx.x * 256 + threadIdx.x;
    int i = t >> 2, c = t & 3;
    if (i >= N_NODES) return;

    const half8* hp = (const half8*)hs;
    half8 pv = ((const half8*)h_part)[(size_t)i * 4 + c];   // low-half partial
    half8 sv = hp[(size_t)i * 4 + c];                       // self term
    float acc[8];
#pragma unroll
    for (int k = 0; k < 8; ++k) acc[k] = (float)pv[k] + (float)sv[k];

    g1_loop(hp, csr_src, row_mid[i], row_ptr[i + 1], c, acc);

    float di = dinv[i];
    float4 ba = *(const float4*)(b1 + c * 8);
    float4 bb = *(const float4*)(b1 + c * 8 + 4);
    half8 o;
    o[0] = (half_t)fmaxf(di * acc[0] + ba.x, 0.f);
    o[1] = (half_t)fmaxf(di * acc[1] + ba.y, 0.f);
    o[2] = (half_t)fmaxf(di * acc[2] + ba.z, 0.f);
    o[3] = (half_t)fmaxf(di * acc[3] + ba.w, 0.f);
    o[4] = (half_t)fmaxf(di * acc[4] + bb.x, 0.f);
    o[5] = (half_t)fmaxf(di * acc[5] + bb.y, 0.f);
    o[6] = (half_t)fmaxf(di * acc[6] + bb.z, 0.f);
    o[7] = (half_t)fmaxf(di * acc[7] + bb.w, 0.f);
    ((half8*)h)[(size_t)i * 4 + c] = o;
}

// ---------------- layer 2 projection ----------------

__global__ __launch_bounds__(256) void k_gemm2(const half_t* __restrict__ h,
                                               const float* __restrict__ Wm,
                                               const float* __restrict__ Wv,
                                               const float* __restrict__ dinv,
                                               half_t* __restrict__ hmv,
                                               float* __restrict__ varr) {
    int i = blockIdx.x * 256 + threadIdx.x;
    if (i >= N_NODES) return;

    const half4* hp = (const half4*)(h + (size_t)i * H_DIM);
    float acc[OUT_DIM + 1];
#pragma unroll
    for (int c = 0; c <= OUT_DIM; ++c) acc[c] = 0.f;

#pragma unroll
    for (int k4 = 0; k4 < H_DIM / 4; ++k4) {
        half4 v = hp[k4];
#pragma unroll
        for (int kk = 0; kk < 4; ++kk) {
            int k = k4 * 4 + kk;
            float hv = (kk == 0) ? (float)v.x : (kk == 1) ? (float)v.y
                     : (kk == 2) ? (float)v.z : (float)v.w;
            const float* wr = Wm + k * OUT_DIM;  // uniform -> s_load
#pragma unroll
            for (int c = 0; c < OUT_DIM; ++c)
                acc[c] = fmaf(hv, wr[c], acc[c]);
            acc[OUT_DIM] = fmaf(hv, Wv[k], acc[OUT_DIM]);
        }
    }

    float di = dinv[i];
    half_t* o = hmv + (size_t)i * OUT_DIM;
#pragma unroll
    for (int c4 = 0; c4 < OUT_DIM / 4; ++c4) {
        half4 ov;
        ov.x = (half_t)(acc[c4 * 4 + 0] * di);
        ov.y = (half_t)(acc[c4 * 4 + 1] * di);
        ov.z = (half_t)(acc[c4 * 4 + 2] * di);
        ov.w = (half_t)(acc[c4 * 4 + 3] * di);
        *(half4*)(o + c4 * 4) = ov;
    }
    varr[i] = acc[OUT_DIM] * di;
}

// ---------------- layer-2 aggregation + finalize ----------------
// 4 lanes/node: lane = (sub, c); sub pair handles half the edge list,
// c = col-group; pipelined cur/nxt index double-buffer.

__global__ __launch_bounds__(256) void k_gather2f(const int* __restrict__ row_ptr,
                                                  const int* __restrict__ csr_src,
                                                  const float* __restrict__ dinv,
                                                  const half_t* __restrict__ hmv,
                                                  const float* __restrict__ varr,
                                                  const float* __restrict__ bm,
                                                  const float* __restrict__ bv,
                                                  float* __restrict__ out) {
    int t = blockIdx.x * 256 + threadIdx.x;
    int i = t >> 2, sub = (t >> 1) & 1, c = t & 1;
    if (i >= N_NODES) return;

    const half8* mp = (const half8*)hmv;         // row = 2 x half8
    int start = row_ptr[i], end = row_ptr[i + 1];
    int mid = start + ((end - start) >> 1);
    int jb = (sub == 0) ? start : mid;           // this sub-pair's edge range
    int je = (sub == 0) ? mid : end;

    float acc[8];
    float va = 0.f;
    if (sub == 0) {                              // self terms once
        half8 sv = mp[(size_t)i * 2 + c];
#pragma unroll
        for (int k = 0; k < 8; ++k) acc[k] = (float)sv[k];
        if (c == 0) va = varr[i];
    } else {
#pragma unroll
        for (int k = 0; k < 8; ++k) acc[k] = 0.f;
    }

    int j = jb;
    int cur[8], nxt[8];
    if (j + 8 <= je) {
#pragma unroll
        for (int u = 0; u < 8; ++u) cur[u] = csr_src[j + u];
    }
    for (; j + 16 <= je; j += 8) {
#pragma unroll
        for (int u = 0; u < 8; ++u) nxt[u] = csr_src[j + 8 + u];   // prefetch
        half8 v[8];
#pragma unroll
        for (int u = 0; u < 8; ++u) v[u] = mp[(size_t)cur[u] * 2 + c];
        float va0 = varr[cur[c]],     va1 = varr[cur[c + 2]];
        float va2 = varr[cur[c + 4]], va3 = varr[cur[c + 6]];
#pragma unroll
        for (int u = 0; u < 8; ++u)
#pragma unroll
            for (int k = 0; k < 8; ++k) acc[k] += (float)v[u][k];
        va += (va0 + va1) + (va2 + va3);
#pragma unroll
        for (int u = 0; u < 8; ++u) cur[u] = nxt[u];
    }
    if (j + 8 <= je) {
        half8 v[8];
#pragma unroll
        for (int u = 0; u < 8; ++u) v[u] = mp[(size_t)cur[u] * 2 + c];
        float va0 = varr[cur[c]],     va1 = varr[cur[c + 2]];
        float va2 = varr[cur[c + 4]], va3 = varr[cur[c + 6]];
#pragma unroll
        for (int u = 0; u < 8; ++u)
#pragma unroll
            for (int k = 0; k < 8; ++k) acc[k] += (float)v[u][k];
        va += (va0 + va1) + (va2 + va3);
        j += 8;
    }
    for (; j < je; ++j) {
        int s = csr_src[j];
        half8 v = mp[(size_t)s * 2 + c];
#pragma unroll
        for (int k = 0; k < 8; ++k) acc[k] += (float)v[k];
        if (((j - jb) & 1) == c) va += varr[s];
    }

    // combine the two sub halves (lane ^2)
#pragma unroll
    for (int k = 0; k < 8; ++k) acc[k] += __shfl_xor(acc[k], 2, 4);
    // var: sum over all 4 lanes
    va += __shfl_xor(va, 1, 4);
    va += __shfl_xor(va, 2, 4);

    float di = dinv[i];
    float4 ba = *(const float4*)(bm + c * 8);
    float4 bb = *(const float4*)(bm + c * 8 + 4);
    float r[8];
    r[0] = di * acc[0] + ba.x;  r[1] = di * acc[1] + ba.y;
    r[2] = di * acc[2] + ba.z;  r[3] = di * acc[3] + ba.w;
    r[4] = di * acc[4] + bb.x;  r[5] = di * acc[5] + bb.y;
    r[6] = di * acc[6] + bb.z;  r[7] = di * acc[7] + bb.w;
    float ssp = 0.f;
#pragma unroll
    for (int k = 0; k < 8; ++k) ssp += r[k] * r[k];
    ssp += __shfl_xor(ssp, 1, 4);                // c0+c1 (subs hold identical copies)
    float inv = rsqrtf(ssp);

    if (sub == 0) {
        float* op = out + (size_t)i * OUT_DIM + c * 8;
        float4 o0, o1;
        o0.x = r[0] * inv; o0.y = r[1] * inv; o0.z = r[2] * inv; o0.w = r[3] * inv;
        o1.x = r[4] * inv; o1.y = r[5] * inv; o1.z = r[6] * inv; o1.w = r[7] * inv;
        *(float4*)op = o0;
        *(float4*)(op + 4) = o1;
        if (c == 0) {
            float xv = di * va + bv[0];
            float sp = fmaxf(xv, 0.f) + log1pf(expf(-fabsf(xv)));   // stable softplus
            out[(size_t)N_NODES * OUT_DIM + i] = sp + 1.0f;
        }
    }
}

// ---------------- launch ----------------

extern "C" void kernel_launch(void* const* d_in, const int* in_sizes, int n_in,
                              void* d_out, int out_size, void* d_ws, size_t ws_size,
                              hipStream_t stream) {
    const float* x  = (const float*)d_in[0];
    const int*   ei = (const int*)d_in[1];
    const float* W1 = (const float*)d_in[2];
    const float* b1 = (const float*)d_in[3];
    const float* Wm = (const float*)d_in[4];
    const float* bm = (const float*)d_in[5];
    const float* Wv = (const float*)d_in[6];
    const float* bv = (const float*)d_in[7];
    float* out = (float*)d_out;

    const int* src = ei;
    const int* dst = ei + N_EDGES;

    // workspace layout; pairs region (12.8 MB) reused for hs + h
    int*   wsi     = (int*)d_ws;
    int*   csr_src = wsi;                               // E                (12.8 MB)
    int*   row_ptr = csr_src + N_EDGES;                 // N+1
    int*   row_mid = row_ptr + N_NODES + 1;             // N
    float* dinv    = (float*)(row_mid + N_NODES);       // N
    int*   hist_g  = (int*)(dinv + N_NODES);            // NHIST = 200192
    int*   sums    = hist_g + NHIST;                    // 1024 (782 used)
    size_t off     = (size_t)(sums + 1024 - wsi);
    off = (off + 3) & ~(size_t)3;                       // 16B align
    unsigned int* pairs = (unsigned int*)(wsi + off);   // E uint32 (12.8 MB)
    half_t* hs     = (half_t*)pairs;                    // N*32 fp16 (6.4 MB)  } overlay
    half_t* h      = hs + (size_t)N_NODES * H_DIM;      // N*32 fp16 (6.4 MB)  } = pairs
    half_t* hmv    = h + (size_t)N_NODES * H_DIM;       // N*16 fp16 (3.2 MB)
    float*  varr   = (float*)(hmv + (size_t)N_NODES * OUT_DIM);  // N fp32 (0.4 MB)
    half_t* h_part = (half_t*)(varr + N_NODES);         // N*32 fp16 (6.4 MB)

    const int B = 256;
    int gN  = (N_NODES + B - 1) / B;        // 391
    int gN4 = (N_NODES * 4 + B - 1) / B;    // 1563

    // --- CSR build (no per-edge global atomics) ---
    k_p1_hist<<<B1, B, 0, stream>>>(dst, hist_g);
    k_scanA<<<SUMS_N, B, 0, stream>>>(hist_g, sums);
    k_scanB<<<1, B, 0, stream>>>(sums);
    k_scanC<<<SUMS_N, B, 0, stream>>>(hist_g, sums);
    k_p3<<<B1, B, 0, stream>>>(src, dst, hist_g, pairs);
    k_p4<<<NB, 512, 0, stream>>>(pairs, hist_g, csr_src, row_ptr, row_mid, dinv);

    // --- layer 1 ---
    k_gemm1<<<gN, B, 0, stream>>>(x, W1, dinv, hs);
    k_gather1A<<<gN4, B, 0, stream>>>(row_ptr, row_mid, csr_src, hs, h_part);
    k_gather1B<<<gN4, B, 0, stream>>>(row_ptr, row_mid, csr_src, dinv, hs, h_part, b1, h);

    // --- layer 2 ---
    k_gemm2<<<gN, B, 0, stream>>>(h, Wm, Wv, dinv, hmv, varr);
    k_gather2f<<<gN4, B, 0, stream>>>(row_ptr, csr_src, dinv, hmv, varr, bm, bv, out);
}